// Round 11
// baseline (161.145 us; speedup 1.0000x reference)
//
#include <hip/hip_runtime.h>
#include <hip/hip_fp16.h>

#define N_NODES 50000
#define EMB 128
#define HID 64
#define NR 16
#define NC 16
#define NE 800000
#define J1 (NR*HID + HID)   /* 1088 = 17*64 */
#define J2 (NR*NC + NC)     /* 272  = 17*16 */
#define CAP 64              /* bucket capacity per dst */
#define NTILE 196           /* dst tiles of 256 nodes (50176 padded) */
#define SEGCAP 4500         /* edges per tile segment (mean 4096, +6.3 sigma) */
#define EPB 8192            /* edges per binA block */
#define NBA 98              /* binA blocks */

typedef _Float16 f16;
typedef __attribute__((ext_vector_type(8))) _Float16 f16x8;
typedef __attribute__((ext_vector_type(4))) _Float16 f16x4;
typedef __attribute__((ext_vector_type(4))) float f32x4;

// ---- fused pre-pass: [cast emb->f16 | build Bt1/Bt2] -----------------------
#define PRE_CAST_BLK 6250              /* 1,600,000 f16x4 groups */
#define PRE_BB_BLK 613
__global__ __launch_bounds__(256)
void k_pre(const float* __restrict__ emb, const float* __restrict__ W1,
           const float* __restrict__ root1, const float* __restrict__ W2,
           const float* __restrict__ root2, f16* __restrict__ embh,
           f16* __restrict__ Bt1, f16* __restrict__ Bt2) {
    int bx = blockIdx.x, tid = threadIdx.x;
    if (bx < PRE_CAST_BLK) {
        int i = bx * 256 + tid;
        if (i < N_NODES * EMB / 4) {
            float4 v = reinterpret_cast<const float4*>(emb)[i];
            f16x4 r = {(f16)v.x, (f16)v.y, (f16)v.z, (f16)v.w};
            reinterpret_cast<f16x4*>(embh)[i] = r;
        }
    } else {
        int idx = (bx - PRE_CAST_BLK) * 256 + tid;
        const int total1 = J1 * EMB;   // 139264
        const int total2 = J2 * HID;   // 17408
        if (idx < total1) {
            int j = idx / EMB, i = idx % EMB;
            float v = (j < NR*HID) ? W1[((size_t)(j >> 6) * EMB + i) * HID + (j & 63)]
                                   : root1[i * HID + (j - NR*HID)];
            Bt1[idx] = (f16)v;
        } else if (idx < total1 + total2) {
            int t = idx - total1;
            int j = t / HID, i = t % HID;
            float v = (j < NR*NC) ? W2[((size_t)(j >> 4) * HID + i) * NC + (j & 15)]
                                  : root2[i * NC + (j - NR*NC)];
            Bt2[t] = (f16)v;
        }
    }
}

// ---- binning phase A: edges -> per-dst-tile segments -----------------------
// LDS-staged: histogram 196 tiles, ONE global atomic per (block,tile) to
// reserve a segment range, then LDS->global scatter (contiguous per tile).
// record = src(16b) | type<<16 (4b) | dstlow<<20 (8b).
__global__ __launch_bounds__(512)
void k_binA(const int* __restrict__ ei, const int* __restrict__ et,
            int* __restrict__ tcnt, unsigned* __restrict__ seg) {
    __shared__ unsigned rec[EPB];
    __shared__ unsigned char tl[EPB];
    __shared__ int hist[256], gbase[256];
    int tid = threadIdx.x;
    for (int i = tid; i < 256; i += 512) hist[i] = 0;
    __syncthreads();
    int e0 = blockIdx.x * EPB;
#pragma unroll
    for (int k = 0; k < EPB / 512; k++) {
        int i = k * 512 + tid, e = e0 + i;
        unsigned t255 = 255, r = 0;
        if (e < NE) {
            int s = ei[e], d = ei[NE + e], t = et[e];
            t255 = (unsigned)(d >> 8);
            r = (unsigned)s | ((unsigned)t << 16) | ((unsigned)(d & 255) << 20);
            atomicAdd(&hist[t255], 1);
        }
        rec[i] = r; tl[i] = (unsigned char)t255;
    }
    __syncthreads();
    if (tid < 256) {
        gbase[tid] = (hist[tid] > 0) ? atomicAdd(&tcnt[tid], hist[tid]) : 0;
        hist[tid] = 0;                      // reuse as local cursor
    }
    __syncthreads();
#pragma unroll
    for (int k = 0; k < EPB / 512; k++) {
        int i = k * 512 + tid;
        unsigned char t = tl[i];
        if (t != 255) {
            int pos = atomicAdd(&hist[t], 1) + gbase[t];
            if (pos < SEGCAP) seg[(size_t)t * SEGCAP + pos] = rec[i];
        }
    }
}

// ---- binning phase B: tile segment -> per-dst buckets (LDS, coalesced out) -
// entry = src*17 + type (Y1 row / 64).
__global__ __launch_bounds__(512)
void k_binB(const int* __restrict__ tcnt, const unsigned* __restrict__ seg,
            int* __restrict__ cur, unsigned* __restrict__ packed) {
    __shared__ int bcnt[256];
    __shared__ unsigned bkt[256 * CAP];     // 64 KB
    int tid = threadIdx.x, b = blockIdx.x;
    for (int i = tid; i < 256; i += 512) bcnt[i] = 0;
    __syncthreads();
    int m = tcnt[b]; if (m > SEGCAP) m = SEGCAP;
    for (int i = tid; i < m; i += 512) {
        unsigned r = seg[(size_t)b * SEGCAP + i];
        int dl = (r >> 20) & 255;
        int pos = atomicAdd(&bcnt[dl], 1);
        if (pos < CAP) bkt[dl * CAP + pos] = (r & 0xFFFFu) * 17u + ((r >> 16) & 15u);
    }
    __syncthreads();
    const uint4* s4 = (const uint4*)bkt;
    uint4* d4 = (uint4*)(packed + (size_t)b * 256 * CAP);
    for (int i = tid; i < 256 * CAP / 4; i += 512) d4[i] = s4[i];
    if (tid < 256) cur[b * 256 + tid] = bcnt[tid];
}

// ---- GEMM1: Y1 = embh @ Bt1^T, bijective XCD swizzle (FETCH 57->13 MB, r10) -
#define NWG1 (391 * 9)      /* 3519 */
__global__ __launch_bounds__(512)
void k_gemm1(const f16* __restrict__ A, const f16* __restrict__ Bt,
             f16* __restrict__ C) {
    constexpr int K = EMB, KP = K + 8;
    __shared__ f16 As[128 * KP];
    __shared__ f16 Bs[128 * KP];
    int wg = blockIdx.x;
    constexpr int qq = NWG1 / 8, rm = NWG1 % 8;    // 439, 7
    int xcd = wg & 7, slot = wg >> 3;
    int vg = (xcd < rm) ? xcd * (qq + 1) + slot
                        : rm * (qq + 1) + (xcd - rm) * qq + slot;
    int m0 = (vg / 9) * 128, n0 = (vg % 9) * 128;
    int tid = threadIdx.x;

    constexpr int V = K / 8;
    for (int idx = tid; idx < 128 * V; idx += 512) {
        int rr = idx / V, c = idx % V;
        f16x8 va = {}, vb = {};
        if (m0 + rr < N_NODES) va = *reinterpret_cast<const f16x8*>(A + (size_t)(m0 + rr) * K + c * 8);
        if (n0 + rr < J1)      vb = *reinterpret_cast<const f16x8*>(Bt + (size_t)(n0 + rr) * K + c * 8);
        *reinterpret_cast<f16x8*>(&As[rr * KP + c * 8]) = va;
        *reinterpret_cast<f16x8*>(&Bs[rr * KP + c * 8]) = vb;
    }
    __syncthreads();

    int w = tid >> 6, lane = tid & 63;
    int wr = (w >> 2) * 64, wc = (w & 3) * 32;
    int lr = lane & 15, lk = (lane >> 4) * 8;

    f32x4 acc[4][2];
#pragma unroll
    for (int mm = 0; mm < 4; mm++)
#pragma unroll
        for (int nn = 0; nn < 2; nn++) acc[mm][nn] = (f32x4){0.f, 0.f, 0.f, 0.f};

#pragma unroll
    for (int k0 = 0; k0 < K; k0 += 32) {
        f16x8 a[4], b[2];
#pragma unroll
        for (int mm = 0; mm < 4; mm++)
            a[mm] = *reinterpret_cast<const f16x8*>(&As[(wr + mm*16 + lr) * KP + k0 + lk]);
#pragma unroll
        for (int nn = 0; nn < 2; nn++)
            b[nn] = *reinterpret_cast<const f16x8*>(&Bs[(wc + nn*16 + lr) * KP + k0 + lk]);
#pragma unroll
        for (int mm = 0; mm < 4; mm++)
#pragma unroll
            for (int nn = 0; nn < 2; nn++)
                acc[mm][nn] = __builtin_amdgcn_mfma_f32_16x16x32_f16(a[mm], b[nn], acc[mm][nn], 0, 0, 0);
    }

    int g = lane >> 4;
#pragma unroll
    for (int mm = 0; mm < 4; mm++)
#pragma unroll
        for (int nn = 0; nn < 2; nn++) {
            int col = n0 + wc + nn*16 + lr;
            if (col < J1) {
#pragma unroll
                for (int q = 0; q < 4; q++) {
                    int row = m0 + wr + mm*16 + g*4 + q;
                    if (row < N_NODES) C[(size_t)row * J1 + col] = (f16)acc[mm][nn][q];
                }
            }
        }
}

// ---- MFMA GEMM for layer 2 -------------------------------------------------
template<int K, typename OutT>
__global__ __launch_bounds__(512)
void k_mfma(const f16* __restrict__ A, const f16* __restrict__ Bt,
            OutT* __restrict__ C, int N, int J) {
    constexpr int KP = K + 8;
    __shared__ f16 As[128 * KP];
    __shared__ f16 Bs[128 * KP];
    int tid = threadIdx.x;
    int m0 = blockIdx.y * 128, n0 = blockIdx.x * 128;

    constexpr int V = K / 8;
    for (int idx = tid; idx < 128 * V; idx += 512) {
        int r = idx / V, c = idx % V;
        f16x8 va = {}, vb = {};
        if (m0 + r < N) va = *reinterpret_cast<const f16x8*>(A + (size_t)(m0 + r) * K + c * 8);
        if (n0 + r < J) vb = *reinterpret_cast<const f16x8*>(Bt + (size_t)(n0 + r) * K + c * 8);
        *reinterpret_cast<f16x8*>(&As[r * KP + c * 8]) = va;
        *reinterpret_cast<f16x8*>(&Bs[r * KP + c * 8]) = vb;
    }
    __syncthreads();

    int w = tid >> 6, lane = tid & 63;
    int wr = (w >> 2) * 64, wc = (w & 3) * 32;
    int lr = lane & 15, lk = (lane >> 4) * 8;

    f32x4 acc[4][2];
#pragma unroll
    for (int mm = 0; mm < 4; mm++)
#pragma unroll
        for (int nn = 0; nn < 2; nn++) acc[mm][nn] = (f32x4){0.f, 0.f, 0.f, 0.f};

#pragma unroll
    for (int k0 = 0; k0 < K; k0 += 32) {
        f16x8 a[4], b[2];
#pragma unroll
        for (int mm = 0; mm < 4; mm++)
            a[mm] = *reinterpret_cast<const f16x8*>(&As[(wr + mm*16 + lr) * KP + k0 + lk]);
#pragma unroll
        for (int nn = 0; nn < 2; nn++)
            b[nn] = *reinterpret_cast<const f16x8*>(&Bs[(wc + nn*16 + lr) * KP + k0 + lk]);
#pragma unroll
        for (int mm = 0; mm < 4; mm++)
#pragma unroll
            for (int nn = 0; nn < 2; nn++)
                acc[mm][nn] = __builtin_amdgcn_mfma_f32_16x16x32_f16(a[mm], b[nn], acc[mm][nn], 0, 0, 0);
    }

    int g = lane >> 4;
#pragma unroll
    for (int mm = 0; mm < 4; mm++)
#pragma unroll
        for (int nn = 0; nn < 2; nn++) {
            int col = n0 + wc + nn*16 + lr;
            if (col < J) {
#pragma unroll
                for (int q = 0; q < 4; q++) {
                    int row = m0 + wr + mm*16 + g*4 + q;
                    if (row < N) C[(size_t)row * J + col] = (OutT)acc[mm][nn][q];
                }
            }
        }
}

// ---- fused layer-1 aggregation + finalize ----------------------------------
// wave/node; 4 edge-groups x 16 channel-quads; f16x4 loads; ballot counts.
__global__ __launch_bounds__(256)
void k_agg1f(const int* __restrict__ cur, const unsigned* __restrict__ packed,
             const f16* __restrict__ Y1, const float* __restrict__ b1,
             f16* __restrict__ X1h) {
    int n = (blockIdx.x * 256 + threadIdx.x) >> 6;
    if (n >= N_NODES) return;
    int lane = threadIdx.x & 63;
    int deg = cur[n]; if (deg > CAP) deg = CAP;
    unsigned my = packed[(size_t)n * CAP + lane];   // stale for lane>=deg, masked
    int tp = (int)(my % 17u);                       // 0..16 always
    float wreg = 0.f;
#pragma unroll
    for (int r = 0; r < 16; r++) {
        unsigned long long b = __ballot(lane < deg && tp == r);
        if (lane == r) wreg = 1.0f / fmaxf((float)__popcll(b), 1.0f);
    }
    float w_my = __shfl(wreg, tp);                  // my edge's mean weight
    int c4 = lane & 15, grp = lane >> 4;
    const f16* Yb = Y1 + c4 * 4;
    float a0 = 0.f, a1 = 0.f, a2 = 0.f, a3 = 0.f;
    for (int i = 0; i < deg; i += 4) {              // wave-uniform bound
        int idx = i + grp;                          // <= 63 always
        unsigned en = __shfl(my, idx);              // all lanes active
        float we = __shfl(w_my, idx);
        if (idx < deg) {
            f16x4 v = *reinterpret_cast<const f16x4*>(Yb + ((size_t)en << 6));
            a0 += we * (float)v[0]; a1 += we * (float)v[1];
            a2 += we * (float)v[2]; a3 += we * (float)v[3];
        }
    }
    a0 += __shfl_xor(a0, 16); a0 += __shfl_xor(a0, 32);
    a1 += __shfl_xor(a1, 16); a1 += __shfl_xor(a1, 32);
    a2 += __shfl_xor(a2, 16); a2 += __shfl_xor(a2, 32);
    a3 += __shfl_xor(a3, 16); a3 += __shfl_xor(a3, 32);
    if (grp == 0) {
        f16x4 rt = *reinterpret_cast<const f16x4*>(Y1 + ((size_t)n * 17 + 16) * 64 + c4 * 4);
        float4 bb = *reinterpret_cast<const float4*>(b1 + c4 * 4);
        f16x4 o = {(f16)fmaxf(a0 + (float)rt[0] + bb.x, 0.f),
                   (f16)fmaxf(a1 + (float)rt[1] + bb.y, 0.f),
                   (f16)fmaxf(a2 + (float)rt[2] + bb.z, 0.f),
                   (f16)fmaxf(a3 + (float)rt[3] + bb.w, 0.f)};
        *reinterpret_cast<f16x4*>(X1h + (size_t)n * HID + c4 * 4) = o;
    }
}

// ---- fused layer-2 aggregation + finalize ----------------------------------
// wave/node; 16 edge-groups x 4 channel-quads; float4 loads (Y2 f32).
__global__ __launch_bounds__(256)
void k_agg2f(const int* __restrict__ cur, const unsigned* __restrict__ packed,
             const float* __restrict__ Y2, const float* __restrict__ b2,
             float* __restrict__ out) {
    int n = (blockIdx.x * 256 + threadIdx.x) >> 6;
    if (n >= N_NODES) return;
    int lane = threadIdx.x & 63;
    int deg = cur[n]; if (deg > CAP) deg = CAP;
    unsigned my = packed[(size_t)n * CAP + lane];
    int tp = (int)(my % 17u);
    float wreg = 0.f;
#pragma unroll
    for (int r = 0; r < 16; r++) {
        unsigned long long b = __ballot(lane < deg && tp == r);
        if (lane == r) wreg = 1.0f / fmaxf((float)__popcll(b), 1.0f);
    }
    float w_my = __shfl(wreg, tp);
    int c4 = lane & 3, grp = lane >> 2;             // 16 groups x 4 quads
    const float* Yb = Y2 + c4 * 4;
    float a0 = 0.f, a1 = 0.f, a2 = 0.f, a3 = 0.f;
    for (int i = 0; i < deg; i += 16) {             // usually 1-2 iterations
        int idx = i + grp;                          // <= 63 always (i<=48,grp<=15)
        unsigned en = __shfl(my, idx);
        float we = __shfl(w_my, idx);
        if (idx < deg) {
            float4 v = *reinterpret_cast<const float4*>(Yb + ((size_t)en << 4));
            a0 += we * v.x; a1 += we * v.y; a2 += we * v.z; a3 += we * v.w;
        }
    }
#pragma unroll
    for (int sh = 4; sh <= 32; sh <<= 1) {
        a0 += __shfl_xor(a0, sh); a1 += __shfl_xor(a1, sh);
        a2 += __shfl_xor(a2, sh); a3 += __shfl_xor(a3, sh);
    }
    if (grp == 0) {                                 // lanes 0..3
        float4 rt = *reinterpret_cast<const float4*>(Y2 + ((size_t)n * 17 + 16) * 16 + c4 * 4);
        float4 bb = *reinterpret_cast<const float4*>(b2 + c4 * 4);
        float4 o;
        o.x = 1.0f / (1.0f + expf(-(a0 + rt.x + bb.x)));
        o.y = 1.0f / (1.0f + expf(-(a1 + rt.y + bb.y)));
        o.z = 1.0f / (1.0f + expf(-(a2 + rt.z + bb.z)));
        o.w = 1.0f / (1.0f + expf(-(a3 + rt.w + bb.w)));
        *reinterpret_cast<float4*>(out + (size_t)n * NC + c4 * 4) = o;
    }
}

extern "C" void kernel_launch(void* const* d_in, const int* in_sizes, int n_in,
                              void* d_out, int out_size, void* d_ws, size_t ws_size,
                              hipStream_t stream) {
    const float* emb   = (const float*)d_in[0];
    const float* W1    = (const float*)d_in[1];
    const float* root1 = (const float*)d_in[2];
    const float* b1    = (const float*)d_in[3];
    const float* W2    = (const float*)d_in[4];
    const float* root2 = (const float*)d_in[5];
    const float* b2    = (const float*)d_in[6];
    const int*   ei    = (const int*)d_in[7];    // [2, NE]: src then dst
    const int*   et    = (const int*)d_in[8];
    float* out = (float*)d_out;

    char* ws = (char*)d_ws;
    // ws layout (bytes), total 134,960,128:
    //   tcnt:     0          .. +1,024        (196 i32, padded)
    //   Bt1:      1,024      .. +278,528      (1088x128 f16)
    //   Bt2:      279,552    .. +34,816       (272x64 f16)
    //   cur:      314,368    .. +200,704      (50176 i32)
    //   packed:   515,072    .. +12,845,056   (50176x64 u32)
    //   embh/X1h: 13,360,128 .. +12,800,000   (embh dies at gemm1; X1h aliases)
    //   Y1/Y2:    26,160,128 .. +108,800,000  (Y1 f16; Y2 f32 aliased)
    //   seg:      aliases Y1 head (3,528,000 B) — dead before gemm1 writes Y1
    int*      tcnt   = (int*)(ws + 0);
    f16*      Bt1    = (f16*)(ws + 1024);
    f16*      Bt2    = (f16*)(ws + 279552);
    int*      cur    = (int*)(ws + 314368);
    unsigned* packed = (unsigned*)(ws + 515072);
    f16*      embh   = (f16*)(ws + 13360128);
    f16*      X1h    = (f16*)(ws + 13360128);    // aliases embh (disjoint lifetime)
    f16*      Y1     = (f16*)(ws + 26160128);
    float*    Y2     = (float*)(ws + 26160128);  // aliases Y1 (dead after agg1f)
    unsigned* seg    = (unsigned*)(ws + 26160128); // aliases Y1 head (pre-gemm1)

    hipMemsetAsync(tcnt, 0, 1024, stream);

    // pre: cast(6250) + build_B(613) = 6863 blocks
    k_pre<<<PRE_CAST_BLK + PRE_BB_BLK, 256, 0, stream>>>(
        emb, W1, root1, W2, root2, embh, Bt1, Bt2);

    k_binA<<<NBA, 512, 0, stream>>>(ei, et, tcnt, seg);
    k_binB<<<NTILE, 512, 0, stream>>>(tcnt, seg, cur, packed);

    k_gemm1<<<NWG1, 512, 0, stream>>>(embh, Bt1, Y1);   // clobbers seg (dead)

    k_agg1f<<<(N_NODES * 64 + 255) / 256, 256, 0, stream>>>(cur, packed, Y1, b1, X1h);

    dim3 g2((J2 + 127) / 128, (N_NODES + 127) / 128);   // 3 x 391
    k_mfma<HID, float><<<g2, 512, 0, stream>>>(X1h, Bt2, Y2, N_NODES, J2);

    k_agg2f<<<(N_NODES * 64 + 255) / 256, 256, 0, stream>>>(cur, packed, Y2, b2, out);
}

// Round 12
// 155.036 us; speedup vs baseline: 1.0394x; 1.0394x over previous
//
#include <hip/hip_runtime.h>
#include <hip/hip_fp16.h>

#define N_NODES 50000
#define EMB 128
#define HID 64
#define NR 16
#define NC 16
#define NE 800000
#define J1 (NR*HID + HID)   /* 1088 = 17*64 */
#define J2 (NR*NC + NC)     /* 272  = 17*16 */
#define CAP 64              /* bucket capacity per dst */
#define NTILE 196           /* dst tiles of 256 nodes (50176 padded) */
#define SEGCAP 4500         /* edges per tile segment (mean 4082, +6.5 sigma) */
#define EPB 8192            /* edges per binA block */
#define NBA 98              /* binA blocks (98*8192 >= 800k) */
#define NWG1 3519           /* gemm blocks: 391 row x 9 col */
#define NWGH (NBA + NWG1)   /* hybrid grid */

typedef _Float16 f16;
typedef __attribute__((ext_vector_type(8))) _Float16 f16x8;
typedef __attribute__((ext_vector_type(4))) _Float16 f16x4;
typedef __attribute__((ext_vector_type(4))) float f32x4;

// ---- build packed transposed fp16 B + zero tcnt (block 612 is idle) --------
__global__ __launch_bounds__(256)
void k_bb(const float* __restrict__ W1, const float* __restrict__ root1,
          const float* __restrict__ W2, const float* __restrict__ root2,
          f16* __restrict__ Bt1, f16* __restrict__ Bt2, int* __restrict__ tcnt) {
    int idx = blockIdx.x * 256 + threadIdx.x;
    const int total1 = J1 * EMB;   // 139264
    const int total2 = J2 * HID;   // 17408
    if (idx < total1) {
        int j = idx / EMB, i = idx % EMB;
        float v = (j < NR*HID) ? W1[((size_t)(j >> 6) * EMB + i) * HID + (j & 63)]
                               : root1[i * HID + (j - NR*HID)];
        Bt1[idx] = (f16)v;
    } else if (idx < total1 + total2) {
        int t = idx - total1;
        int j = t / HID, i = t % HID;
        float v = (j < NR*NC) ? W2[((size_t)(j >> 4) * HID + i) * NC + (j & 15)]
                              : root2[i * NC + (j - NR*NC)];
        Bt2[t] = (f16)v;
    } else if (blockIdx.x == 612 && threadIdx.x < 256) {
        tcnt[threadIdx.x] = 0;
    }
}

// ---- hybrid: GEMM1 (Y1 = f16(emb) @ Bt1^T) + binA edge binning -------------
// wg<98: binA (LDS histogram -> 1 global atomic/(block,tile) -> contiguous
// segment scatter). wg>=98: gemm tile, bijective XCD swizzle (r10: FETCH
// 57->13MB verified) with fp32 A staged + in-register f16 convert.
__global__ __launch_bounds__(512)
void k_hyb(const float* __restrict__ A, const f16* __restrict__ Bt,
           f16* __restrict__ C, const int* __restrict__ ei,
           const int* __restrict__ et, int* __restrict__ tcnt,
           unsigned* __restrict__ seg) {
    constexpr int K = EMB, KP = K + 8;
    __shared__ __align__(16) char smem[128 * KP * 2 * 2];   // 69,632 B union
    int wg = blockIdx.x, tid = threadIdx.x;

    if (wg < NBA) {                     // ================ binA path ========
        unsigned*      rec   = (unsigned*)smem;              // 32 KB
        unsigned char* tl    = (unsigned char*)(smem + 32768); // 8 KB
        int*           hist  = (int*)(smem + 40960);         // 1 KB
        int*           gbase = (int*)(smem + 41984);         // 1 KB
        for (int i = tid; i < 256; i += 512) hist[i] = 0;
        __syncthreads();
        int e0 = wg * EPB;
#pragma unroll
        for (int k = 0; k < EPB / 512; k++) {
            int i = k * 512 + tid, e = e0 + i;
            unsigned t255 = 255, r = 0;
            if (e < NE) {
                int s = ei[e], d = ei[NE + e], t = et[e];
                t255 = (unsigned)(d >> 8);
                r = (unsigned)s | ((unsigned)t << 16) | ((unsigned)(d & 255) << 20);
                atomicAdd(&hist[t255], 1);
            }
            rec[i] = r; tl[i] = (unsigned char)t255;
        }
        __syncthreads();
        if (tid < 256) {
            gbase[tid] = (hist[tid] > 0) ? atomicAdd(&tcnt[tid], hist[tid]) : 0;
            hist[tid] = 0;                  // reuse as local cursor
        }
        __syncthreads();
#pragma unroll
        for (int k = 0; k < EPB / 512; k++) {
            int i = k * 512 + tid;
            unsigned char t = tl[i];
            if (t != 255) {
                int pos = atomicAdd(&hist[t], 1) + gbase[t];
                if (pos < SEGCAP) seg[(size_t)t * SEGCAP + pos] = rec[i];
            }
        }
        return;
    }
    // ================ gemm path ================
    f16* As = (f16*)smem;
    f16* Bs = As + 128 * KP;
    int g = wg - NBA;
    constexpr int qq = NWG1 / 8, rm = NWG1 % 8;    // 439, 7
    int x = g & 7, slot = g >> 3;
    int vg = (x < rm) ? x * (qq + 1) + slot
                      : rm * (qq + 1) + (x - rm) * qq + slot;
    int m0 = (vg / 9) * 128, n0 = (vg % 9) * 128;

    for (int idx = tid; idx < 128 * 32; idx += 512) {      // A: f32 -> f16
        int r = idx >> 5, c = idx & 31;
        float4 v = make_float4(0.f, 0.f, 0.f, 0.f);
        if (m0 + r < N_NODES) v = reinterpret_cast<const float4*>(A)[(size_t)(m0 + r) * 32 + c];
        f16x4 h = {(f16)v.x, (f16)v.y, (f16)v.z, (f16)v.w};
        *reinterpret_cast<f16x4*>(&As[r * KP + c * 4]) = h;
    }
    for (int idx = tid; idx < 128 * 16; idx += 512) {      // B: f16x8
        int r = idx >> 4, c = idx & 15;
        f16x8 vb = {};
        if (n0 + r < J1) vb = *reinterpret_cast<const f16x8*>(Bt + (size_t)(n0 + r) * K + c * 8);
        *reinterpret_cast<f16x8*>(&Bs[r * KP + c * 8]) = vb;
    }
    __syncthreads();

    int w = tid >> 6, lane = tid & 63;
    int wr = (w >> 2) * 64, wc = (w & 3) * 32;
    int lr = lane & 15, lk = (lane >> 4) * 8;

    f32x4 acc[4][2];
#pragma unroll
    for (int mm = 0; mm < 4; mm++)
#pragma unroll
        for (int nn = 0; nn < 2; nn++) acc[mm][nn] = (f32x4){0.f, 0.f, 0.f, 0.f};

#pragma unroll
    for (int k0 = 0; k0 < K; k0 += 32) {
        f16x8 a[4], b[2];
#pragma unroll
        for (int mm = 0; mm < 4; mm++)
            a[mm] = *reinterpret_cast<const f16x8*>(&As[(wr + mm*16 + lr) * KP + k0 + lk]);
#pragma unroll
        for (int nn = 0; nn < 2; nn++)
            b[nn] = *reinterpret_cast<const f16x8*>(&Bs[(wc + nn*16 + lr) * KP + k0 + lk]);
#pragma unroll
        for (int mm = 0; mm < 4; mm++)
#pragma unroll
            for (int nn = 0; nn < 2; nn++)
                acc[mm][nn] = __builtin_amdgcn_mfma_f32_16x16x32_f16(a[mm], b[nn], acc[mm][nn], 0, 0, 0);
    }

    int gq = lane >> 4;
#pragma unroll
    for (int mm = 0; mm < 4; mm++)
#pragma unroll
        for (int nn = 0; nn < 2; nn++) {
            int col = n0 + wc + nn*16 + lr;
            if (col < J1) {
#pragma unroll
                for (int q = 0; q < 4; q++) {
                    int row = m0 + wr + mm*16 + gq*4 + q;
                    if (row < N_NODES) C[(size_t)row * J1 + col] = (f16)acc[mm][nn][q];
                }
            }
        }
}

// ---- binB: tile segment -> per-dst buckets (LDS, coalesced out) ------------
// entry = src*17 + type (Y1 row / 64).
__global__ __launch_bounds__(512)
void k_binB(const int* __restrict__ tcnt, const unsigned* __restrict__ seg,
            int* __restrict__ cur, unsigned* __restrict__ packed) {
    __shared__ int bcnt[256];
    __shared__ unsigned bkt[256 * CAP];     // 64 KB
    int tid = threadIdx.x, b = blockIdx.x;
    for (int i = tid; i < 256; i += 512) bcnt[i] = 0;
    __syncthreads();
    int m = tcnt[b]; if (m > SEGCAP) m = SEGCAP;
    for (int i = tid; i < m; i += 512) {
        unsigned r = seg[(size_t)b * SEGCAP + i];
        int dl = (r >> 20) & 255;
        int pos = atomicAdd(&bcnt[dl], 1);
        if (pos < CAP) bkt[dl * CAP + pos] = (r & 0xFFFFu) * 17u + ((r >> 16) & 15u);
    }
    __syncthreads();
    const uint4* s4 = (const uint4*)bkt;
    uint4* d4 = (uint4*)(packed + (size_t)b * 256 * CAP);
    for (int i = tid; i < 256 * CAP / 4; i += 512) d4[i] = s4[i];
    if (tid < 256) cur[b * 256 + tid] = bcnt[tid];
}

// ---- MFMA GEMM for layer 2 -------------------------------------------------
template<int K, typename OutT>
__global__ __launch_bounds__(512)
void k_mfma(const f16* __restrict__ A, const f16* __restrict__ Bt,
            OutT* __restrict__ C, int N, int J) {
    constexpr int KP = K + 8;
    __shared__ f16 As[128 * KP];
    __shared__ f16 Bs[128 * KP];
    int tid = threadIdx.x;
    int m0 = blockIdx.y * 128, n0 = blockIdx.x * 128;

    constexpr int V = K / 8;
    for (int idx = tid; idx < 128 * V; idx += 512) {
        int r = idx / V, c = idx % V;
        f16x8 va = {}, vb = {};
        if (m0 + r < N) va = *reinterpret_cast<const f16x8*>(A + (size_t)(m0 + r) * K + c * 8);
        if (n0 + r < J) vb = *reinterpret_cast<const f16x8*>(Bt + (size_t)(n0 + r) * K + c * 8);
        *reinterpret_cast<f16x8*>(&As[r * KP + c * 8]) = va;
        *reinterpret_cast<f16x8*>(&Bs[r * KP + c * 8]) = vb;
    }
    __syncthreads();

    int w = tid >> 6, lane = tid & 63;
    int wr = (w >> 2) * 64, wc = (w & 3) * 32;
    int lr = lane & 15, lk = (lane >> 4) * 8;

    f32x4 acc[4][2];
#pragma unroll
    for (int mm = 0; mm < 4; mm++)
#pragma unroll
        for (int nn = 0; nn < 2; nn++) acc[mm][nn] = (f32x4){0.f, 0.f, 0.f, 0.f};

#pragma unroll
    for (int k0 = 0; k0 < K; k0 += 32) {
        f16x8 a[4], b[2];
#pragma unroll
        for (int mm = 0; mm < 4; mm++)
            a[mm] = *reinterpret_cast<const f16x8*>(&As[(wr + mm*16 + lr) * KP + k0 + lk]);
#pragma unroll
        for (int nn = 0; nn < 2; nn++)
            b[nn] = *reinterpret_cast<const f16x8*>(&Bs[(wc + nn*16 + lr) * KP + k0 + lk]);
#pragma unroll
        for (int mm = 0; mm < 4; mm++)
#pragma unroll
            for (int nn = 0; nn < 2; nn++)
                acc[mm][nn] = __builtin_amdgcn_mfma_f32_16x16x32_f16(a[mm], b[nn], acc[mm][nn], 0, 0, 0);
    }

    int g = lane >> 4;
#pragma unroll
    for (int mm = 0; mm < 4; mm++)
#pragma unroll
        for (int nn = 0; nn < 2; nn++) {
            int col = n0 + wc + nn*16 + lr;
            if (col < J) {
#pragma unroll
                for (int q = 0; q < 4; q++) {
                    int row = m0 + wr + mm*16 + g*4 + q;
                    if (row < N) C[(size_t)row * J + col] = (OutT)acc[mm][nn][q];
                }
            }
        }
}

// ---- fused layer-1 aggregation + finalize ----------------------------------
// wave/node; 4 edge-groups x 16 channel-quads; f16x4 loads; ballot counts.
__global__ __launch_bounds__(256)
void k_agg1f(const int* __restrict__ cur, const unsigned* __restrict__ packed,
             const f16* __restrict__ Y1, const float* __restrict__ b1,
             f16* __restrict__ X1h) {
    int n = (blockIdx.x * 256 + threadIdx.x) >> 6;
    if (n >= N_NODES) return;
    int lane = threadIdx.x & 63;
    int deg = cur[n]; if (deg > CAP) deg = CAP;
    unsigned my = packed[(size_t)n * CAP + lane];   // stale for lane>=deg, masked
    int tp = (int)(my % 17u);                       // 0..16 always
    float wreg = 0.f;
#pragma unroll
    for (int r = 0; r < 16; r++) {
        unsigned long long b = __ballot(lane < deg && tp == r);
        if (lane == r) wreg = 1.0f / fmaxf((float)__popcll(b), 1.0f);
    }
    float w_my = __shfl(wreg, tp);                  // my edge's mean weight
    int c4 = lane & 15, grp = lane >> 4;
    const f16* Yb = Y1 + c4 * 4;
    float a0 = 0.f, a1 = 0.f, a2 = 0.f, a3 = 0.f;
    for (int i = 0; i < deg; i += 4) {              // wave-uniform bound
        int idx = i + grp;                          // <= 63 always
        unsigned en = __shfl(my, idx);              // all lanes active
        float we = __shfl(w_my, idx);
        if (idx < deg) {
            f16x4 v = *reinterpret_cast<const f16x4*>(Yb + ((size_t)en << 6));
            a0 += we * (float)v[0]; a1 += we * (float)v[1];
            a2 += we * (float)v[2]; a3 += we * (float)v[3];
        }
    }
    a0 += __shfl_xor(a0, 16); a0 += __shfl_xor(a0, 32);
    a1 += __shfl_xor(a1, 16); a1 += __shfl_xor(a1, 32);
    a2 += __shfl_xor(a2, 16); a2 += __shfl_xor(a2, 32);
    a3 += __shfl_xor(a3, 16); a3 += __shfl_xor(a3, 32);
    if (grp == 0) {
        f16x4 rt = *reinterpret_cast<const f16x4*>(Y1 + ((size_t)n * 17 + 16) * 64 + c4 * 4);
        float4 bb = *reinterpret_cast<const float4*>(b1 + c4 * 4);
        f16x4 o = {(f16)fmaxf(a0 + (float)rt[0] + bb.x, 0.f),
                   (f16)fmaxf(a1 + (float)rt[1] + bb.y, 0.f),
                   (f16)fmaxf(a2 + (float)rt[2] + bb.z, 0.f),
                   (f16)fmaxf(a3 + (float)rt[3] + bb.w, 0.f)};
        *reinterpret_cast<f16x4*>(X1h + (size_t)n * HID + c4 * 4) = o;
    }
}

// ---- fused layer-2 aggregation + finalize ----------------------------------
// wave/node; 16 edge-groups x 4 channel-quads; float4 loads (Y2 f32).
__global__ __launch_bounds__(256)
void k_agg2f(const int* __restrict__ cur, const unsigned* __restrict__ packed,
             const float* __restrict__ Y2, const float* __restrict__ b2,
             float* __restrict__ out) {
    int n = (blockIdx.x * 256 + threadIdx.x) >> 6;
    if (n >= N_NODES) return;
    int lane = threadIdx.x & 63;
    int deg = cur[n]; if (deg > CAP) deg = CAP;
    unsigned my = packed[(size_t)n * CAP + lane];
    int tp = (int)(my % 17u);
    float wreg = 0.f;
#pragma unroll
    for (int r = 0; r < 16; r++) {
        unsigned long long b = __ballot(lane < deg && tp == r);
        if (lane == r) wreg = 1.0f / fmaxf((float)__popcll(b), 1.0f);
    }
    float w_my = __shfl(wreg, tp);
    int c4 = lane & 3, grp = lane >> 2;             // 16 groups x 4 quads
    const float* Yb = Y2 + c4 * 4;
    float a0 = 0.f, a1 = 0.f, a2 = 0.f, a3 = 0.f;
    for (int i = 0; i < deg; i += 16) {             // usually 1-2 iterations
        int idx = i + grp;                          // <= 63 always (i<=48,grp<=15)
        unsigned en = __shfl(my, idx);
        float we = __shfl(w_my, idx);
        if (idx < deg) {
            float4 v = *reinterpret_cast<const float4*>(Yb + ((size_t)en << 4));
            a0 += we * v.x; a1 += we * v.y; a2 += we * v.z; a3 += we * v.w;
        }
    }
#pragma unroll
    for (int sh = 4; sh <= 32; sh <<= 1) {
        a0 += __shfl_xor(a0, sh); a1 += __shfl_xor(a1, sh);
        a2 += __shfl_xor(a2, sh); a3 += __shfl_xor(a3, sh);
    }
    if (grp == 0) {                                 // lanes 0..3
        float4 rt = *reinterpret_cast<const float4*>(Y2 + ((size_t)n * 17 + 16) * 16 + c4 * 4);
        float4 bb = *reinterpret_cast<const float4*>(b2 + c4 * 4);
        float4 o;
        o.x = 1.0f / (1.0f + expf(-(a0 + rt.x + bb.x)));
        o.y = 1.0f / (1.0f + expf(-(a1 + rt.y + bb.y)));
        o.z = 1.0f / (1.0f + expf(-(a2 + rt.z + bb.z)));
        o.w = 1.0f / (1.0f + expf(-(a3 + rt.w + bb.w)));
        *reinterpret_cast<float4*>(out + (size_t)n * NC + c4 * 4) = o;
    }
}

extern "C" void kernel_launch(void* const* d_in, const int* in_sizes, int n_in,
                              void* d_out, int out_size, void* d_ws, size_t ws_size,
                              hipStream_t stream) {
    const float* emb   = (const float*)d_in[0];
    const float* W1    = (const float*)d_in[1];
    const float* root1 = (const float*)d_in[2];
    const float* b1    = (const float*)d_in[3];
    const float* W2    = (const float*)d_in[4];
    const float* root2 = (const float*)d_in[5];
    const float* b2    = (const float*)d_in[6];
    const int*   ei    = (const int*)d_in[7];    // [2, NE]: src then dst
    const int*   et    = (const int*)d_in[8];
    float* out = (float*)d_out;

    char* ws = (char*)d_ws;
    // ws layout (bytes), total 132,088,128:
    //   tcnt:    0          .. +1,024        (196 i32, padded)
    //   Bt1:     1,024      .. +278,528      (1088x128 f16)
    //   Bt2:     279,552    .. +34,816       (272x64 f16)
    //   cur:     314,368    .. +200,704      (50176 i32)
    //   packed:  515,072    .. +12,845,056   (50176x64 u32)
    //   seg:     13,360,128 .. +3,528,000    (196x4500 u32)
    //   X1h:     16,888,128 .. +6,400,000    (50000x64 f16)
    //   Y1/Y2:   23,288,128 .. +108,800,000  (Y1 f16; Y2 f32 aliased)
    int*      tcnt   = (int*)(ws + 0);
    f16*      Bt1    = (f16*)(ws + 1024);
    f16*      Bt2    = (f16*)(ws + 279552);
    int*      cur    = (int*)(ws + 314368);
    unsigned* packed = (unsigned*)(ws + 515072);
    unsigned* seg    = (unsigned*)(ws + 13360128);
    f16*      X1h    = (f16*)(ws + 16888128);
    f16*      Y1     = (f16*)(ws + 23288128);
    float*    Y2     = (float*)(ws + 23288128);   // aliases Y1 (dead after agg1f)

    // no memsets: tcnt zeroed by k_bb block 612; cur/packed fully written by binB
    k_bb<<<613, 256, 0, stream>>>(W1, root1, W2, root2, Bt1, Bt2, tcnt);

    // hybrid: 98 binA blocks (dispatched first, all XCDs) + 3519 swizzled gemm
    k_hyb<<<NWGH, 512, 0, stream>>>(emb, Bt1, Y1, ei, et, tcnt, seg);

    k_binB<<<NTILE, 512, 0, stream>>>(tcnt, seg, cur, packed);

    k_agg1f<<<(N_NODES * 64 + 255) / 256, 256, 0, stream>>>(cur, packed, Y1, b1, X1h);

    dim3 g2((J2 + 127) / 128, (N_NODES + 127) / 128);   // 3 x 391
    k_mfma<HID, float><<<g2, 512, 0, stream>>>(X1h, Bt2, Y2, N_NODES, J2);

    k_agg2f<<<(N_NODES * 64 + 255) / 256, 256, 0, stream>>>(cur, packed, Y2, b2, out);
}